// Round 1
// baseline (1094.861 us; speedup 1.0000x reference)
//
#include <hip/hip_runtime.h>

#define N_NODES 50000
#define N_EDGES 800000
#define IN_FEATS 256
#define HIDDEN 128
#define OUT_FEATS 64

// ---------------------------------------------------------------- degrees
__global__ __launch_bounds__(256) void deg_kernel(
    const int* __restrict__ src, const int* __restrict__ dst,
    float* __restrict__ deg_out, float* __restrict__ deg_in) {
  int i = blockIdx.x * 256 + threadIdx.x;
  if (i < N_EDGES) {
    atomicAdd(&deg_out[src[i]], 1.0f);
    atomicAdd(&deg_in[dst[i]], 1.0f);
  }
}

// in-place: d[i] = rsqrt(max(d[i],1))  over 2*N_NODES floats (deg_out|deg_in)
__global__ __launch_bounds__(256) void norm_kernel(float* __restrict__ d) {
  int i = blockIdx.x * 256 + threadIdx.x;
  if (i < 2 * N_NODES) d[i] = rsqrtf(fmaxf(d[i], 1.0f));
}

// ---------------------------------------------------------------- GEMM
// M[row, :] = (X[row, :] * ns[row]) @ W     X:[N_NODES,K]  W:[K,COLS]
// 32-row x COLS-col tile per block, 256 threads, K staged in KB=64 chunks.
template <int K, int COLS>
__global__ __launch_bounds__(256) void gemm_scaled(
    const float* __restrict__ X, const float* __restrict__ W,
    const float* __restrict__ ns, float* __restrict__ M) {
  constexpr int ROWS = 32;
  constexpr int KB = 64;
  constexpr int COLG = COLS / 4;        // float4 col-groups: 32 or 16
  constexpr int ROWLANES = 256 / COLG;  // 8 or 16
  constexpr int RPT = ROWS / ROWLANES;  // rows per thread: 4 or 2

  __shared__ float xs[ROWS * KB];     // 8 KB
  __shared__ float wsm[KB * COLS];    // 32 KB (COLS=128) / 16 KB (COLS=64)

  const int tid = threadIdx.x;
  const int colg = tid % COLG;
  const int rl = tid / COLG;
  const int row0 = blockIdx.x * ROWS;

  float acc[RPT][4];
#pragma unroll
  for (int r = 0; r < RPT; ++r)
#pragma unroll
    for (int c = 0; c < 4; ++c) acc[r][c] = 0.0f;

  for (int k0 = 0; k0 < K; k0 += KB) {
    // stage X tile (scaled by ns[row]); ROWS*KB/4 float4s
#pragma unroll
    for (int f = tid; f < ROWS * KB / 4; f += 256) {
      int r = f / (KB / 4);
      int c4 = f % (KB / 4);
      int row = row0 + r;
      float4 v = make_float4(0.f, 0.f, 0.f, 0.f);
      if (row < N_NODES) {
        v = *(const float4*)(X + (long)row * K + k0 + c4 * 4);
        float s = ns[row];
        v.x *= s; v.y *= s; v.z *= s; v.w *= s;
      }
      *(float4*)(xs + r * KB + c4 * 4) = v;
    }
    // stage W tile; KB*COLS/4 float4s
#pragma unroll
    for (int f = tid; f < KB * COLS / 4; f += 256) {
      int r = f / (COLS / 4);
      int c4 = f % (COLS / 4);
      *(float4*)(wsm + r * COLS + c4 * 4) =
          *(const float4*)(W + (long)(k0 + r) * COLS + c4 * 4);
    }
    __syncthreads();

#pragma unroll 8
    for (int k = 0; k < KB; ++k) {
      float4 wv = *(const float4*)(wsm + k * COLS + colg * 4);
#pragma unroll
      for (int r = 0; r < RPT; ++r) {
        float xv = xs[(rl + r * ROWLANES) * KB + k];
        acc[r][0] += xv * wv.x;
        acc[r][1] += xv * wv.y;
        acc[r][2] += xv * wv.z;
        acc[r][3] += xv * wv.w;
      }
    }
    __syncthreads();
  }

#pragma unroll
  for (int r = 0; r < RPT; ++r) {
    int row = row0 + rl + r * ROWLANES;
    if (row < N_NODES) {
      *(float4*)(M + (long)row * COLS + colg * 4) =
          make_float4(acc[r][0], acc[r][1], acc[r][2], acc[r][3]);
    }
  }
}

// ---------------------------------------------------------------- scatter
// agg[dst[e], :] += M[src[e], :]   one wave per edge, 4 edges per block.
template <int F>
__global__ __launch_bounds__(256) void scatter_kernel(
    const float* __restrict__ M, const int* __restrict__ src,
    const int* __restrict__ dst, float* __restrict__ agg) {
  const int wave = threadIdx.x >> 6;
  const int lane = threadIdx.x & 63;
  const long e = (long)blockIdx.x * 4 + wave;
  if (e >= N_EDGES) return;
  const int s = src[e];
  const int d = dst[e];
  const float* ms = M + (long)s * F;
  float* ad = agg + (long)d * F;
  if (F == 128) {
    float2 v = *(const float2*)(ms + lane * 2);
    atomicAdd(ad + lane * 2, v.x);
    atomicAdd(ad + lane * 2 + 1, v.y);
  } else {
    atomicAdd(ad + lane, ms[lane]);
  }
}

// ---------------------------------------------------------------- epilogues
// h = relu(agg * norm_dst[row] + b)   (float4 over N_NODES*HIDDEN)
__global__ __launch_bounds__(256) void finish1_kernel(
    float* __restrict__ h, const float* __restrict__ nd,
    const float* __restrict__ b) {
  int i4 = blockIdx.x * 256 + threadIdx.x;
  const int n4 = N_NODES * HIDDEN / 4;
  if (i4 >= n4) return;
  int row = i4 / (HIDDEN / 4);
  int c4 = i4 % (HIDDEN / 4);
  float s = nd[row];
  float4 v = *(float4*)(h + (long)i4 * 4);
  float4 bb = *(const float4*)(b + c4 * 4);
  v.x = fmaxf(v.x * s + bb.x, 0.f);
  v.y = fmaxf(v.y * s + bb.y, 0.f);
  v.z = fmaxf(v.z * s + bb.z, 0.f);
  v.w = fmaxf(v.w * s + bb.w, 0.f);
  *(float4*)(h + (long)i4 * 4) = v;
}

// out = out * norm_dst[row] + b   (no relu), in place on d_out
__global__ __launch_bounds__(256) void finish2_kernel(
    float* __restrict__ out, const float* __restrict__ nd,
    const float* __restrict__ b) {
  int i4 = blockIdx.x * 256 + threadIdx.x;
  const int n4 = N_NODES * OUT_FEATS / 4;
  if (i4 >= n4) return;
  int row = i4 / (OUT_FEATS / 4);
  int c4 = i4 % (OUT_FEATS / 4);
  float s = nd[row];
  float4 v = *(float4*)(out + (long)i4 * 4);
  float4 bb = *(const float4*)(b + c4 * 4);
  v.x = v.x * s + bb.x;
  v.y = v.y * s + bb.y;
  v.z = v.z * s + bb.z;
  v.w = v.w * s + bb.w;
  *(float4*)(out + (long)i4 * 4) = v;
}

extern "C" void kernel_launch(void* const* d_in, const int* in_sizes, int n_in,
                              void* d_out, int out_size, void* d_ws,
                              size_t ws_size, hipStream_t stream) {
  const float* x = (const float*)d_in[0];
  const int* src = (const int*)d_in[1];
  const int* dst = (const int*)d_in[2];
  const float* W1 = (const float*)d_in[3];
  const float* b1 = (const float*)d_in[4];
  const float* W2 = (const float*)d_in[5];
  const float* b2 = (const float*)d_in[6];
  float* out = (float*)d_out;

  // workspace layout (floats)
  float* ws = (float*)d_ws;
  float* deg = ws;                    // [2*N_NODES]  -> becomes norm_src|norm_dst
  float* norm_src = ws;               // [N_NODES]
  float* norm_dst = ws + N_NODES;     // [N_NODES]
  float* m1 = ws + 2 * N_NODES;                        // [N_NODES*HIDDEN]
  float* h1 = m1 + (long)N_NODES * HIDDEN;             // [N_NODES*HIDDEN] agg1 then h1
  float* m2 = h1 + (long)N_NODES * HIDDEN;             // [N_NODES*OUT_FEATS]

  // ---- norms
  hipMemsetAsync(deg, 0, 2 * N_NODES * sizeof(float), stream);
  deg_kernel<<<(N_EDGES + 255) / 256, 256, 0, stream>>>(src, dst, deg,
                                                        deg + N_NODES);
  norm_kernel<<<(2 * N_NODES + 255) / 256, 256, 0, stream>>>(deg);

  // ---- layer 1
  gemm_scaled<IN_FEATS, HIDDEN>
      <<<(N_NODES + 31) / 32, 256, 0, stream>>>(x, W1, norm_src, m1);
  hipMemsetAsync(h1, 0, (long)N_NODES * HIDDEN * sizeof(float), stream);
  scatter_kernel<HIDDEN>
      <<<(N_EDGES + 3) / 4, 256, 0, stream>>>(m1, src, dst, h1);
  finish1_kernel<<<(N_NODES * HIDDEN / 4 + 255) / 256, 256, 0, stream>>>(
      h1, norm_dst, b1);

  // ---- layer 2
  gemm_scaled<HIDDEN, OUT_FEATS>
      <<<(N_NODES + 31) / 32, 256, 0, stream>>>(h1, W2, norm_src, m2);
  hipMemsetAsync(out, 0, (long)N_NODES * OUT_FEATS * sizeof(float), stream);
  scatter_kernel<OUT_FEATS>
      <<<(N_EDGES + 3) / 4, 256, 0, stream>>>(m2, src, dst, out);
  finish2_kernel<<<(N_NODES * OUT_FEATS / 4 + 255) / 256, 256, 0, stream>>>(
      out, norm_dst, b2);
}

// Round 2
// 398.176 us; speedup vs baseline: 2.7497x; 2.7497x over previous
//
#include <hip/hip_runtime.h>

#define N_NODES 50000
#define N_EDGES 800000
#define IN_FEATS 256
#define HIDDEN 128
#define OUT_FEATS 64

// ------------------------------------------------------------- degrees (int)
__global__ __launch_bounds__(256) void deg_kernel(
    const int* __restrict__ src, const int* __restrict__ dst,
    int* __restrict__ deg_out, int* __restrict__ deg_in) {
  int i = blockIdx.x * 256 + threadIdx.x;
  if (i < N_EDGES) {
    atomicAdd(&deg_out[src[i]], 1);
    atomicAdd(&deg_in[dst[i]], 1);
  }
}

// norm_src[i] = rsqrt(max(deg_out,1)); norm_dst[i] = rsqrt(max(deg_in,1))
__global__ __launch_bounds__(256) void norm_kernel(
    const int* __restrict__ deg_out, const int* __restrict__ deg_in,
    float* __restrict__ norm_src, float* __restrict__ norm_dst) {
  int i = blockIdx.x * 256 + threadIdx.x;
  if (i < N_NODES) {
    norm_src[i] = rsqrtf((float)max(deg_out[i], 1));
    norm_dst[i] = rsqrtf((float)max(deg_in[i], 1));
  }
}

// ------------------------------------------------------------- prefix scan
// 3-kernel exclusive scan of deg_in[N_NODES] -> rowptr[N_NODES+1]
__global__ __launch_bounds__(256) void scan1(const int* __restrict__ deg,
                                             int* __restrict__ partial) {
  __shared__ int sd[256];
  int i = blockIdx.x * 256 + threadIdx.x;
  sd[threadIdx.x] = (i < N_NODES) ? deg[i] : 0;
  __syncthreads();
  for (int s = 128; s > 0; s >>= 1) {
    if (threadIdx.x < s) sd[threadIdx.x] += sd[threadIdx.x + s];
    __syncthreads();
  }
  if (threadIdx.x == 0) partial[blockIdx.x] = sd[0];
}

__global__ __launch_bounds__(256) void scan2(int* __restrict__ partial,
                                             int nb) {
  __shared__ int sd[256];
  int v = (threadIdx.x < nb) ? partial[threadIdx.x] : 0;
  sd[threadIdx.x] = v;
  __syncthreads();
  for (int off = 1; off < 256; off <<= 1) {
    int t = sd[threadIdx.x] +
            ((threadIdx.x >= off) ? sd[threadIdx.x - off] : 0);
    __syncthreads();
    sd[threadIdx.x] = t;
    __syncthreads();
  }
  if (threadIdx.x < nb) partial[threadIdx.x] = sd[threadIdx.x] - v;  // excl
}

__global__ __launch_bounds__(256) void scan3(const int* __restrict__ deg,
                                             const int* __restrict__ partial,
                                             int* __restrict__ rowptr) {
  __shared__ int sd[256];
  int i = blockIdx.x * 256 + threadIdx.x;
  int v = (i < N_NODES) ? deg[i] : 0;
  sd[threadIdx.x] = v;
  __syncthreads();
  for (int off = 1; off < 256; off <<= 1) {
    int t = sd[threadIdx.x] +
            ((threadIdx.x >= off) ? sd[threadIdx.x - off] : 0);
    __syncthreads();
    sd[threadIdx.x] = t;
    __syncthreads();
  }
  if (i < N_NODES) rowptr[i] = partial[blockIdx.x] + sd[threadIdx.x] - v;
  if (blockIdx.x == 0 && threadIdx.x == 0) rowptr[N_NODES] = N_EDGES;
}

// ------------------------------------------------------------- CSR fill
__global__ __launch_bounds__(256) void fill_csr(
    const int* __restrict__ src, const int* __restrict__ dst,
    const int* __restrict__ rowptr, int* __restrict__ cursor,
    int* __restrict__ col) {
  int e = blockIdx.x * 256 + threadIdx.x;
  if (e < N_EDGES) {
    int d = dst[e];
    int pos = rowptr[d] + atomicAdd(&cursor[d], 1);
    col[pos] = src[e];
  }
}

// ---------------------------------------------------------------- GEMM
// M[row, :] = (X[row, :] * ns[row]) @ W     X:[N_NODES,K]  W:[K,COLS]
template <int K, int COLS>
__global__ __launch_bounds__(256) void gemm_scaled(
    const float* __restrict__ X, const float* __restrict__ W,
    const float* __restrict__ ns, float* __restrict__ M) {
  constexpr int ROWS = 32;
  constexpr int KB = 64;
  constexpr int COLG = COLS / 4;        // float4 col-groups: 32 or 16
  constexpr int ROWLANES = 256 / COLG;  // 8 or 16
  constexpr int RPT = ROWS / ROWLANES;  // rows per thread: 4 or 2

  __shared__ float xs[ROWS * KB];
  __shared__ float wsm[KB * COLS];

  const int tid = threadIdx.x;
  const int colg = tid % COLG;
  const int rl = tid / COLG;
  const int row0 = blockIdx.x * ROWS;

  float acc[RPT][4];
#pragma unroll
  for (int r = 0; r < RPT; ++r)
#pragma unroll
    for (int c = 0; c < 4; ++c) acc[r][c] = 0.0f;

  for (int k0 = 0; k0 < K; k0 += KB) {
#pragma unroll
    for (int f = tid; f < ROWS * KB / 4; f += 256) {
      int r = f / (KB / 4);
      int c4 = f % (KB / 4);
      int row = row0 + r;
      float4 v = make_float4(0.f, 0.f, 0.f, 0.f);
      if (row < N_NODES) {
        v = *(const float4*)(X + (long)row * K + k0 + c4 * 4);
        float s = ns[row];
        v.x *= s; v.y *= s; v.z *= s; v.w *= s;
      }
      *(float4*)(xs + r * KB + c4 * 4) = v;
    }
#pragma unroll
    for (int f = tid; f < KB * COLS / 4; f += 256) {
      int r = f / (COLS / 4);
      int c4 = f % (COLS / 4);
      *(float4*)(wsm + r * COLS + c4 * 4) =
          *(const float4*)(W + (long)(k0 + r) * COLS + c4 * 4);
    }
    __syncthreads();

#pragma unroll 8
    for (int k = 0; k < KB; ++k) {
      float4 wv = *(const float4*)(wsm + k * COLS + colg * 4);
#pragma unroll
      for (int r = 0; r < RPT; ++r) {
        float xv = xs[(rl + r * ROWLANES) * KB + k];
        acc[r][0] += xv * wv.x;
        acc[r][1] += xv * wv.y;
        acc[r][2] += xv * wv.z;
        acc[r][3] += xv * wv.w;
      }
    }
    __syncthreads();
  }

#pragma unroll
  for (int r = 0; r < RPT; ++r) {
    int row = row0 + rl + r * ROWLANES;
    if (row < N_NODES) {
      *(float4*)(M + (long)row * COLS + colg * 4) =
          make_float4(acc[r][0], acc[r][1], acc[r][2], acc[r][3]);
    }
  }
}

// ------------------------------------------------------------- gather-agg
// out[n,:] = act( (sum_{e in CSR[n]} M[col[e],:]) * nd[n] + b )
// One wave per node; F=128 -> float2/lane, F=64 -> float/lane.
template <int F, bool RELU>
__global__ __launch_bounds__(256) void gather_kernel(
    const float* __restrict__ M, const int* __restrict__ rowptr,
    const int* __restrict__ col, const float* __restrict__ nd,
    const float* __restrict__ b, float* __restrict__ out) {
  const int wave = threadIdx.x >> 6;
  const int lane = threadIdx.x & 63;
  const int n = blockIdx.x * 4 + wave;
  if (n >= N_NODES) return;
  const int beg = rowptr[n];
  const int end = rowptr[n + 1];

  if (F == 128) {
    float ax = 0.f, ay = 0.f;
    int i = beg;
    for (; i + 3 < end; i += 4) {
      int s0 = col[i], s1 = col[i + 1], s2 = col[i + 2], s3 = col[i + 3];
      float2 v0 = *(const float2*)(M + (long)s0 * F + lane * 2);
      float2 v1 = *(const float2*)(M + (long)s1 * F + lane * 2);
      float2 v2 = *(const float2*)(M + (long)s2 * F + lane * 2);
      float2 v3 = *(const float2*)(M + (long)s3 * F + lane * 2);
      ax += v0.x + v1.x + v2.x + v3.x;
      ay += v0.y + v1.y + v2.y + v3.y;
    }
    for (; i < end; ++i) {
      float2 v = *(const float2*)(M + (long)col[i] * F + lane * 2);
      ax += v.x;
      ay += v.y;
    }
    float s = nd[n];
    float2 bb = *(const float2*)(b + lane * 2);
    float ox = ax * s + bb.x;
    float oy = ay * s + bb.y;
    if (RELU) { ox = fmaxf(ox, 0.f); oy = fmaxf(oy, 0.f); }
    *(float2*)(out + (long)n * F + lane * 2) = make_float2(ox, oy);
  } else {
    float acc = 0.f;
    int i = beg;
    for (; i + 3 < end; i += 4) {
      int s0 = col[i], s1 = col[i + 1], s2 = col[i + 2], s3 = col[i + 3];
      acc += M[(long)s0 * F + lane] + M[(long)s1 * F + lane] +
             M[(long)s2 * F + lane] + M[(long)s3 * F + lane];
    }
    for (; i < end; ++i) acc += M[(long)col[i] * F + lane];
    float o = acc * nd[n] + b[lane];
    if (RELU) o = fmaxf(o, 0.f);
    out[(long)n * F + lane] = o;
  }
}

extern "C" void kernel_launch(void* const* d_in, const int* in_sizes, int n_in,
                              void* d_out, int out_size, void* d_ws,
                              size_t ws_size, hipStream_t stream) {
  const float* x = (const float*)d_in[0];
  const int* src = (const int*)d_in[1];
  const int* dst = (const int*)d_in[2];
  const float* W1 = (const float*)d_in[3];
  const float* b1 = (const float*)d_in[4];
  const float* W2 = (const float*)d_in[5];
  const float* b2 = (const float*)d_in[6];
  float* out = (float*)d_out;

  // ---- workspace layout (all 4-byte elems; offsets keep 16B alignment)
  int* wi = (int*)d_ws;
  int* deg_out_i = wi;                   // [50000]
  int* deg_in_i = wi + 50000;            // [50000]
  int* partial = wi + 100000;            // [256]
  int* rowptr = wi + 100256;             // [50001] (padded to 50004)
  int* cursor = wi + 150260;             // [50000]
  int* col = wi + 200260;                // [800000]
  float* wf = (float*)d_ws + 1000260;
  float* norm_src = wf;                  // [50000]
  float* norm_dst = wf + 50000;          // [50000]
  float* m1 = wf + 100000;               // [50000*128]
  float* h1 = m1 + (long)N_NODES * HIDDEN;  // [50000*128]
  float* m2 = m1;                        // reuse m1 after gather1

  const int nb_nodes = (N_NODES + 255) / 256;  // 196

  // ---- degrees + norms + CSR
  hipMemsetAsync(deg_out_i, 0, 100000 * sizeof(int), stream);
  hipMemsetAsync(cursor, 0, 50000 * sizeof(int), stream);
  deg_kernel<<<(N_EDGES + 255) / 256, 256, 0, stream>>>(src, dst, deg_out_i,
                                                        deg_in_i);
  norm_kernel<<<nb_nodes, 256, 0, stream>>>(deg_out_i, deg_in_i, norm_src,
                                            norm_dst);
  scan1<<<nb_nodes, 256, 0, stream>>>(deg_in_i, partial);
  scan2<<<1, 256, 0, stream>>>(partial, nb_nodes);
  scan3<<<nb_nodes, 256, 0, stream>>>(deg_in_i, partial, rowptr);
  fill_csr<<<(N_EDGES + 255) / 256, 256, 0, stream>>>(src, dst, rowptr, cursor,
                                                      col);

  // ---- layer 1: m1 = (x*ns)@W1 ; h1 = relu(gather(m1)*nd + b1)
  gemm_scaled<IN_FEATS, HIDDEN>
      <<<(N_NODES + 31) / 32, 256, 0, stream>>>(x, W1, norm_src, m1);
  gather_kernel<HIDDEN, true>
      <<<(N_NODES + 3) / 4, 256, 0, stream>>>(m1, rowptr, col, norm_dst, b1,
                                              h1);

  // ---- layer 2: m2 = (h1*ns)@W2 ; out = gather(m2)*nd + b2
  gemm_scaled<HIDDEN, OUT_FEATS>
      <<<(N_NODES + 31) / 32, 256, 0, stream>>>(h1, W2, norm_src, m2);
  gather_kernel<OUT_FEATS, false>
      <<<(N_NODES + 3) / 4, 256, 0, stream>>>(m2, rowptr, col, norm_dst, b2,
                                              out);
}

// Round 3
// 330.734 us; speedup vs baseline: 3.3104x; 1.2039x over previous
//
#include <hip/hip_runtime.h>

#define N_NODES 50000
#define N_EDGES 800000
#define IN_FEATS 256
#define HIDDEN 128
#define OUT_FEATS 64

typedef _Float16 f16;
typedef _Float16 f16x2 __attribute__((ext_vector_type(2)));
typedef _Float16 f16x8 __attribute__((ext_vector_type(8)));
typedef float f32x4 __attribute__((ext_vector_type(4)));

// ------------------------------------------------------------- degrees (int)
__global__ __launch_bounds__(256) void deg_kernel(
    const int* __restrict__ src, const int* __restrict__ dst,
    int* __restrict__ deg_out, int* __restrict__ deg_in) {
  int i = blockIdx.x * 256 + threadIdx.x;
  if (i < N_EDGES) {
    atomicAdd(&deg_out[src[i]], 1);
    atomicAdd(&deg_in[dst[i]], 1);
  }
}

__global__ __launch_bounds__(256) void norm_kernel(
    const int* __restrict__ deg_out, const int* __restrict__ deg_in,
    float* __restrict__ norm_src, float* __restrict__ norm_dst) {
  int i = blockIdx.x * 256 + threadIdx.x;
  if (i < N_NODES) {
    norm_src[i] = rsqrtf((float)max(deg_out[i], 1));
    norm_dst[i] = rsqrtf((float)max(deg_in[i], 1));
  }
}

// ------------------------------------------------------------- prefix scan
__global__ __launch_bounds__(256) void scan1(const int* __restrict__ deg,
                                             int* __restrict__ partial) {
  __shared__ int sd[256];
  int i = blockIdx.x * 256 + threadIdx.x;
  sd[threadIdx.x] = (i < N_NODES) ? deg[i] : 0;
  __syncthreads();
  for (int s = 128; s > 0; s >>= 1) {
    if (threadIdx.x < s) sd[threadIdx.x] += sd[threadIdx.x + s];
    __syncthreads();
  }
  if (threadIdx.x == 0) partial[blockIdx.x] = sd[0];
}

__global__ __launch_bounds__(256) void scan2(int* __restrict__ partial,
                                             int nb) {
  __shared__ int sd[256];
  int v = (threadIdx.x < nb) ? partial[threadIdx.x] : 0;
  sd[threadIdx.x] = v;
  __syncthreads();
  for (int off = 1; off < 256; off <<= 1) {
    int t = sd[threadIdx.x] +
            ((threadIdx.x >= off) ? sd[threadIdx.x - off] : 0);
    __syncthreads();
    sd[threadIdx.x] = t;
    __syncthreads();
  }
  if (threadIdx.x < nb) partial[threadIdx.x] = sd[threadIdx.x] - v;  // excl
}

__global__ __launch_bounds__(256) void scan3(const int* __restrict__ deg,
                                             const int* __restrict__ partial,
                                             int* __restrict__ rowptr) {
  __shared__ int sd[256];
  int i = blockIdx.x * 256 + threadIdx.x;
  int v = (i < N_NODES) ? deg[i] : 0;
  sd[threadIdx.x] = v;
  __syncthreads();
  for (int off = 1; off < 256; off <<= 1) {
    int t = sd[threadIdx.x] +
            ((threadIdx.x >= off) ? sd[threadIdx.x - off] : 0);
    __syncthreads();
    sd[threadIdx.x] = t;
    __syncthreads();
  }
  if (i < N_NODES) rowptr[i] = partial[blockIdx.x] + sd[threadIdx.x] - v;
  if (blockIdx.x == 0 && threadIdx.x == 0) rowptr[N_NODES] = N_EDGES;
}

// ------------------------------------------------------------- CSR fill
__global__ __launch_bounds__(256) void fill_csr(
    const int* __restrict__ src, const int* __restrict__ dst,
    const int* __restrict__ rowptr, int* __restrict__ cursor,
    int* __restrict__ col) {
  int e = blockIdx.x * 256 + threadIdx.x;
  if (e < N_EDGES) {
    int d = dst[e];
    int pos = rowptr[d] + atomicAdd(&cursor[d], 1);
    col[pos] = src[e];
  }
}

// ------------------------------------------------------------- W transpose
// W1 [256][128] f32 -> W1T [128][256] f16 ; W2 [128][64] f32 -> W2T [64][128]
__global__ __launch_bounds__(256) void wtrans(const float* __restrict__ W1,
                                              const float* __restrict__ W2,
                                              f16* __restrict__ W1T,
                                              f16* __restrict__ W2T) {
  int i = blockIdx.x * 256 + threadIdx.x;
  if (i < 128 * 256) {  // output-major over W1T
    int n = i >> 8, k = i & 255;
    W1T[i] = (f16)W1[k * 128 + n];
  } else if (i < 128 * 256 + 64 * 128) {
    int j = i - 128 * 256;
    int n = j >> 7, k = j & 127;
    W2T[j] = (f16)W2[k * 64 + n];
  }
}

// ------------------------------------------------------------- MFMA GEMM
// Mout[r,:] = (X[r,:] * (FP32IN ? ns[r] : 1)) @ WT^T
// X: [N_NODES][K] (f32 if FP32IN else f16); WT: [NC][K] f16; Mout: [N_NODES][NC] f16
// 4 waves/block, 32 rows/wave (two 16-row A-blocks), NT=NC/16 col tiles.
// A/B frag layout (m89/m120-verified): elem j of lane -> [m=lane&15][k=(lane>>4)*8+j]
// C/D: col=lane&15, row=(lane>>4)*4+reg.
template <int K, int NC, bool FP32IN>
__global__ __launch_bounds__(256) void gemm_mfma(
    const void* __restrict__ Xv, const f16* __restrict__ WT,
    const float* __restrict__ ns, f16* __restrict__ Mout) {
  constexpr int KI = K / 32;
  constexpr int NT = NC / 16;
  const int wave = threadIdx.x >> 6;
  const int lane = threadIdx.x & 63;
  const int m = lane & 15;
  const int q = lane >> 4;
  const int wrow0 = blockIdx.x * 128 + wave * 32;

  const int ra0 = min(wrow0 + m, N_NODES - 1);
  const int ra1 = min(wrow0 + 16 + m, N_NODES - 1);
  const float s0 = FP32IN ? ns[ra0] : 0.f;
  const float s1 = FP32IN ? ns[ra1] : 0.f;

  f32x4 acc[2][NT];
#pragma unroll
  for (int ab = 0; ab < 2; ++ab)
#pragma unroll
    for (int t = 0; t < NT; ++t) acc[ab][t] = (f32x4){0.f, 0.f, 0.f, 0.f};

#pragma unroll
  for (int ki = 0; ki < KI; ++ki) {
    const int kbase = ki * 32 + q * 8;
    f16x8 a0, a1;
    if (FP32IN) {
      const float* X = (const float*)Xv;
      const float* p0 = X + (long)ra0 * K + kbase;
      const float* p1 = X + (long)ra1 * K + kbase;
      float4 u0 = *(const float4*)p0;
      float4 u1 = *(const float4*)(p0 + 4);
      float4 w0 = *(const float4*)p1;
      float4 w1 = *(const float4*)(p1 + 4);
      a0[0] = (f16)(u0.x * s0); a0[1] = (f16)(u0.y * s0);
      a0[2] = (f16)(u0.z * s0); a0[3] = (f16)(u0.w * s0);
      a0[4] = (f16)(u1.x * s0); a0[5] = (f16)(u1.y * s0);
      a0[6] = (f16)(u1.z * s0); a0[7] = (f16)(u1.w * s0);
      a1[0] = (f16)(w0.x * s1); a1[1] = (f16)(w0.y * s1);
      a1[2] = (f16)(w0.z * s1); a1[3] = (f16)(w0.w * s1);
      a1[4] = (f16)(w1.x * s1); a1[5] = (f16)(w1.y * s1);
      a1[6] = (f16)(w1.z * s1); a1[7] = (f16)(w1.w * s1);
    } else {
      const f16* X = (const f16*)Xv;
      a0 = *(const f16x8*)(X + (long)ra0 * K + kbase);
      a1 = *(const f16x8*)(X + (long)ra1 * K + kbase);
    }
#pragma unroll
    for (int t = 0; t < NT; ++t) {
      f16x8 b = *(const f16x8*)(WT + (long)(t * 16 + m) * K + kbase);
      acc[0][t] =
          __builtin_amdgcn_mfma_f32_16x16x32_f16(a0, b, acc[0][t], 0, 0, 0);
      acc[1][t] =
          __builtin_amdgcn_mfma_f32_16x16x32_f16(a1, b, acc[1][t], 0, 0, 0);
    }
  }

#pragma unroll
  for (int ab = 0; ab < 2; ++ab)
#pragma unroll
    for (int r = 0; r < 4; ++r) {
      int row = wrow0 + ab * 16 + q * 4 + r;
      if (row < N_NODES) {
#pragma unroll
        for (int t = 0; t < NT; ++t)
          Mout[(long)row * NC + t * 16 + m] = (f16)acc[ab][t][r];
      }
    }
}

// ------------------------------------------------------------- gather-agg
// gather1: h1p[n,:] = f16( relu( (sum M1[col]) * nd[n] + b1 ) * ns[n] )
__global__ __launch_bounds__(256) void gather1_kernel(
    const f16* __restrict__ M, const int* __restrict__ rowptr,
    const int* __restrict__ col, const float* __restrict__ nd,
    const float* __restrict__ ns, const float* __restrict__ b,
    f16* __restrict__ out) {
  const int wave = threadIdx.x >> 6;
  const int lane = threadIdx.x & 63;
  const int n = blockIdx.x * 4 + wave;
  if (n >= N_NODES) return;
  const int beg = rowptr[n];
  const int end = rowptr[n + 1];

  float ax = 0.f, ay = 0.f;
  int i = beg;
  for (; i + 3 < end; i += 4) {
    int s0 = col[i], s1 = col[i + 1], s2 = col[i + 2], s3 = col[i + 3];
    f16x2 v0 = *(const f16x2*)(M + (long)s0 * HIDDEN + lane * 2);
    f16x2 v1 = *(const f16x2*)(M + (long)s1 * HIDDEN + lane * 2);
    f16x2 v2 = *(const f16x2*)(M + (long)s2 * HIDDEN + lane * 2);
    f16x2 v3 = *(const f16x2*)(M + (long)s3 * HIDDEN + lane * 2);
    ax += (float)v0[0] + (float)v1[0] + (float)v2[0] + (float)v3[0];
    ay += (float)v0[1] + (float)v1[1] + (float)v2[1] + (float)v3[1];
  }
  for (; i < end; ++i) {
    f16x2 v = *(const f16x2*)(M + (long)col[i] * HIDDEN + lane * 2);
    ax += (float)v[0];
    ay += (float)v[1];
  }
  float s = nd[n];
  float sn = ns[n];
  float ox = fmaxf(ax * s + b[lane * 2], 0.f) * sn;
  float oy = fmaxf(ay * s + b[lane * 2 + 1], 0.f) * sn;
  f16x2 o;
  o[0] = (f16)ox;
  o[1] = (f16)oy;
  *(f16x2*)(out + (long)n * HIDDEN + lane * 2) = o;
}

// gather2: out[n,:] = (sum M2[col]) * nd[n] + b2   (fp32 out)
__global__ __launch_bounds__(256) void gather2_kernel(
    const f16* __restrict__ M, const int* __restrict__ rowptr,
    const int* __restrict__ col, const float* __restrict__ nd,
    const float* __restrict__ b, float* __restrict__ out) {
  const int wave = threadIdx.x >> 6;
  const int lane = threadIdx.x & 63;
  const int n = blockIdx.x * 4 + wave;
  if (n >= N_NODES) return;
  const int beg = rowptr[n];
  const int end = rowptr[n + 1];

  float acc = 0.f;
  int i = beg;
  for (; i + 3 < end; i += 4) {
    int s0 = col[i], s1 = col[i + 1], s2 = col[i + 2], s3 = col[i + 3];
    acc += (float)M[(long)s0 * OUT_FEATS + lane] +
           (float)M[(long)s1 * OUT_FEATS + lane] +
           (float)M[(long)s2 * OUT_FEATS + lane] +
           (float)M[(long)s3 * OUT_FEATS + lane];
  }
  for (; i < end; ++i) acc += (float)M[(long)col[i] * OUT_FEATS + lane];
  out[(long)n * OUT_FEATS + lane] = acc * nd[n] + b[lane];
}

extern "C" void kernel_launch(void* const* d_in, const int* in_sizes, int n_in,
                              void* d_out, int out_size, void* d_ws,
                              size_t ws_size, hipStream_t stream) {
  const float* x = (const float*)d_in[0];
  const int* src = (const int*)d_in[1];
  const int* dst = (const int*)d_in[2];
  const float* W1 = (const float*)d_in[3];
  const float* b1 = (const float*)d_in[4];
  const float* W2 = (const float*)d_in[5];
  const float* b2 = (const float*)d_in[6];
  float* out = (float*)d_out;

  // ---- workspace layout
  int* wi = (int*)d_ws;
  int* deg_out_i = wi;          // [50000]
  int* deg_in_i = wi + 50000;   // [50000]
  int* partial = wi + 100000;   // [256]
  int* rowptr = wi + 100256;    // [50001] (pad to 50004)
  int* cursor = wi + 150260;    // [50000]
  int* col = wi + 200260;       // [800000]  -> ends at int 1000260
  float* wf = (float*)d_ws + 1000260;
  float* norm_src = wf;               // [50000]
  float* norm_dst = wf + 50000;       // [50000]
  f16* fh = (f16*)(wf + 100000);
  f16* W1T = fh;                      // [128*256]
  f16* W2T = fh + 128 * 256;          // [64*128]
  f16* m1 = fh + 128 * 256 + 64 * 128;         // [50048*128]
  f16* h1p = m1 + (long)50048 * 128;           // [50048*128]
  f16* m2 = h1p + (long)50048 * 128;           // [50048*64]

  const int nb_nodes = (N_NODES + 255) / 256;  // 196

  // ---- degrees + norms + CSR
  hipMemsetAsync(deg_out_i, 0, 100000 * sizeof(int), stream);
  hipMemsetAsync(cursor, 0, 50000 * sizeof(int), stream);
  deg_kernel<<<(N_EDGES + 255) / 256, 256, 0, stream>>>(src, dst, deg_out_i,
                                                        deg_in_i);
  norm_kernel<<<nb_nodes, 256, 0, stream>>>(deg_out_i, deg_in_i, norm_src,
                                            norm_dst);
  scan1<<<nb_nodes, 256, 0, stream>>>(deg_in_i, partial);
  scan2<<<1, 256, 0, stream>>>(partial, nb_nodes);
  scan3<<<nb_nodes, 256, 0, stream>>>(deg_in_i, partial, rowptr);
  fill_csr<<<(N_EDGES + 255) / 256, 256, 0, stream>>>(src, dst, rowptr, cursor,
                                                      col);
  wtrans<<<(128 * 256 + 64 * 128 + 255) / 256, 256, 0, stream>>>(W1, W2, W1T,
                                                                 W2T);

  // ---- layer 1
  gemm_mfma<IN_FEATS, HIDDEN, true>
      <<<(N_NODES + 127) / 128, 256, 0, stream>>>(x, W1T, norm_src, m1);
  gather1_kernel<<<(N_NODES + 3) / 4, 256, 0, stream>>>(m1, rowptr, col,
                                                        norm_dst, norm_src, b1,
                                                        h1p);

  // ---- layer 2
  gemm_mfma<HIDDEN, OUT_FEATS, false>
      <<<(N_NODES + 127) / 128, 256, 0, stream>>>(h1p, W2T, norm_src, m2);
  gather2_kernel<<<(N_NODES + 3) / 4, 256, 0, stream>>>(m2, rowptr, col,
                                                        norm_dst, b2, out);
}

// Round 4
// 330.276 us; speedup vs baseline: 3.3150x; 1.0014x over previous
//
#include <hip/hip_runtime.h>

#define N_NODES 50000
#define N_EDGES 800000
#define IN_FEATS 256
#define HIDDEN 128
#define OUT_FEATS 64
#define NCOPY 16

typedef _Float16 f16;
typedef _Float16 f16x2 __attribute__((ext_vector_type(2)));
typedef _Float16 f16x8 __attribute__((ext_vector_type(8)));
typedef float f32x4 __attribute__((ext_vector_type(4)));

// ---------------------------------------------------------- privatized hist
// Copy c = blockIdx&15: with round-robin block->XCD dispatch, each copy's
// cache lines stay in one XCD's L2 (no cross-XCD atomic line bouncing).
__global__ __launch_bounds__(256) void hist_kernel(
    const int* __restrict__ src, const int* __restrict__ dst,
    int* __restrict__ hist_src, int* __restrict__ hist_dst) {
  int e = blockIdx.x * 256 + threadIdx.x;
  int c = blockIdx.x & (NCOPY - 1);
  if (e < N_EDGES) {
    atomicAdd(&hist_src[c * N_NODES + src[e]], 1);
    atomicAdd(&hist_dst[c * N_NODES + dst[e]], 1);
  }
}

// sum copies -> norms; turn hist_dst into exclusive prefix over copies.
__global__ __launch_bounds__(256) void reduce_kernel(
    const int* __restrict__ hist_src, int* __restrict__ hist_dst,
    int* __restrict__ deg_in, float* __restrict__ norm_src,
    float* __restrict__ norm_dst) {
  int n = blockIdx.x * 256 + threadIdx.x;
  if (n >= N_NODES) return;
  int so = 0;
#pragma unroll
  for (int c = 0; c < NCOPY; ++c) so += hist_src[c * N_NODES + n];
  norm_src[n] = rsqrtf((float)max(so, 1));
  int run = 0;
#pragma unroll
  for (int c = 0; c < NCOPY; ++c) {
    int t = hist_dst[c * N_NODES + n];
    hist_dst[c * N_NODES + n] = run;  // exclusive prefix (per-copy base)
    run += t;
  }
  deg_in[n] = run;
  norm_dst[n] = rsqrtf((float)max(run, 1));
}

// ------------------------------------------------------------- prefix scan
__global__ __launch_bounds__(256) void scan1(const int* __restrict__ deg,
                                             int* __restrict__ partial) {
  __shared__ int sd[256];
  int i = blockIdx.x * 256 + threadIdx.x;
  sd[threadIdx.x] = (i < N_NODES) ? deg[i] : 0;
  __syncthreads();
  for (int s = 128; s > 0; s >>= 1) {
    if (threadIdx.x < s) sd[threadIdx.x] += sd[threadIdx.x + s];
    __syncthreads();
  }
  if (threadIdx.x == 0) partial[blockIdx.x] = sd[0];
}

__global__ __launch_bounds__(256) void scan2(int* __restrict__ partial,
                                             int nb) {
  __shared__ int sd[256];
  int v = (threadIdx.x < nb) ? partial[threadIdx.x] : 0;
  sd[threadIdx.x] = v;
  __syncthreads();
  for (int off = 1; off < 256; off <<= 1) {
    int t = sd[threadIdx.x] +
            ((threadIdx.x >= off) ? sd[threadIdx.x - off] : 0);
    __syncthreads();
    sd[threadIdx.x] = t;
    __syncthreads();
  }
  if (threadIdx.x < nb) partial[threadIdx.x] = sd[threadIdx.x] - v;  // excl
}

__global__ __launch_bounds__(256) void scan3(const int* __restrict__ deg,
                                             const int* __restrict__ partial,
                                             int* __restrict__ rowptr) {
  __shared__ int sd[256];
  int i = blockIdx.x * 256 + threadIdx.x;
  int v = (i < N_NODES) ? deg[i] : 0;
  sd[threadIdx.x] = v;
  __syncthreads();
  for (int off = 1; off < 256; off <<= 1) {
    int t = sd[threadIdx.x] +
            ((threadIdx.x >= off) ? sd[threadIdx.x - off] : 0);
    __syncthreads();
    sd[threadIdx.x] = t;
    __syncthreads();
  }
  if (i < N_NODES) rowptr[i] = partial[blockIdx.x] + sd[threadIdx.x] - v;
  if (blockIdx.x == 0 && threadIdx.x == 0) rowptr[N_NODES] = N_EDGES;
}

// cursor[c][n] = rowptr[n] + pref[c][n]  (absolute write base per copy)
__global__ __launch_bounds__(256) void cursor_init(
    const int* __restrict__ rowptr, const int* __restrict__ pref,
    int* __restrict__ cursor) {
  int i = blockIdx.x * 256 + threadIdx.x;
  if (i < NCOPY * N_NODES) {
    int n = i % N_NODES;
    cursor[i] = rowptr[n] + pref[i];
  }
}

// ------------------------------------------------------------- CSR fill
// Copy-class mapping MUST match hist_kernel (same grid, same e->block map).
__global__ __launch_bounds__(256) void fill_csr(
    const int* __restrict__ src, const int* __restrict__ dst,
    int* __restrict__ cursor, int* __restrict__ col) {
  int e = blockIdx.x * 256 + threadIdx.x;
  int c = blockIdx.x & (NCOPY - 1);
  if (e < N_EDGES) {
    int pos = atomicAdd(&cursor[c * N_NODES + dst[e]], 1);
    col[pos] = src[e];
  }
}

// ------------------------------------------------------------- W transpose
__global__ __launch_bounds__(256) void wtrans(const float* __restrict__ W1,
                                              const float* __restrict__ W2,
                                              f16* __restrict__ W1T,
                                              f16* __restrict__ W2T) {
  int i = blockIdx.x * 256 + threadIdx.x;
  if (i < 128 * 256) {
    int n = i >> 8, k = i & 255;
    W1T[i] = (f16)W1[k * 128 + n];
  } else if (i < 128 * 256 + 64 * 128) {
    int j = i - 128 * 256;
    int n = j >> 7, k = j & 127;
    W2T[j] = (f16)W2[k * 64 + n];
  }
}

// ------------------------------------------------------------- MFMA GEMM
template <int K, int NC, bool FP32IN>
__global__ __launch_bounds__(256) void gemm_mfma(
    const void* __restrict__ Xv, const f16* __restrict__ WT,
    const float* __restrict__ ns, f16* __restrict__ Mout) {
  constexpr int KI = K / 32;
  constexpr int NT = NC / 16;
  const int wave = threadIdx.x >> 6;
  const int lane = threadIdx.x & 63;
  const int m = lane & 15;
  const int q = lane >> 4;
  const int wrow0 = blockIdx.x * 128 + wave * 32;

  const int ra0 = min(wrow0 + m, N_NODES - 1);
  const int ra1 = min(wrow0 + 16 + m, N_NODES - 1);
  const float s0 = FP32IN ? ns[ra0] : 0.f;
  const float s1 = FP32IN ? ns[ra1] : 0.f;

  f32x4 acc[2][NT];
#pragma unroll
  for (int ab = 0; ab < 2; ++ab)
#pragma unroll
    for (int t = 0; t < NT; ++t) acc[ab][t] = (f32x4){0.f, 0.f, 0.f, 0.f};

#pragma unroll
  for (int ki = 0; ki < KI; ++ki) {
    const int kbase = ki * 32 + q * 8;
    f16x8 a0, a1;
    if (FP32IN) {
      const float* X = (const float*)Xv;
      const float* p0 = X + (long)ra0 * K + kbase;
      const float* p1 = X + (long)ra1 * K + kbase;
      float4 u0 = *(const float4*)p0;
      float4 u1 = *(const float4*)(p0 + 4);
      float4 w0 = *(const float4*)p1;
      float4 w1 = *(const float4*)(p1 + 4);
      a0[0] = (f16)(u0.x * s0); a0[1] = (f16)(u0.y * s0);
      a0[2] = (f16)(u0.z * s0); a0[3] = (f16)(u0.w * s0);
      a0[4] = (f16)(u1.x * s0); a0[5] = (f16)(u1.y * s0);
      a0[6] = (f16)(u1.z * s0); a0[7] = (f16)(u1.w * s0);
      a1[0] = (f16)(w0.x * s1); a1[1] = (f16)(w0.y * s1);
      a1[2] = (f16)(w0.z * s1); a1[3] = (f16)(w0.w * s1);
      a1[4] = (f16)(w1.x * s1); a1[5] = (f16)(w1.y * s1);
      a1[6] = (f16)(w1.z * s1); a1[7] = (f16)(w1.w * s1);
    } else {
      const f16* X = (const f16*)Xv;
      a0 = *(const f16x8*)(X + (long)ra0 * K + kbase);
      a1 = *(const f16x8*)(X + (long)ra1 * K + kbase);
    }
#pragma unroll
    for (int t = 0; t < NT; ++t) {
      f16x8 b = *(const f16x8*)(WT + (long)(t * 16 + m) * K + kbase);
      acc[0][t] =
          __builtin_amdgcn_mfma_f32_16x16x32_f16(a0, b, acc[0][t], 0, 0, 0);
      acc[1][t] =
          __builtin_amdgcn_mfma_f32_16x16x32_f16(a1, b, acc[1][t], 0, 0, 0);
    }
  }

#pragma unroll
  for (int ab = 0; ab < 2; ++ab)
#pragma unroll
    for (int r = 0; r < 4; ++r) {
      int row = wrow0 + ab * 16 + q * 4 + r;
      if (row < N_NODES) {
#pragma unroll
        for (int t = 0; t < NT; ++t)
          Mout[(long)row * NC + t * 16 + m] = (f16)acc[ab][t][r];
      }
    }
}

// ------------------------------------------------------------- gather-agg
__global__ __launch_bounds__(256) void gather1_kernel(
    const f16* __restrict__ M, const int* __restrict__ rowptr,
    const int* __restrict__ col, const float* __restrict__ nd,
    const float* __restrict__ ns, const float* __restrict__ b,
    f16* __restrict__ out) {
  const int wave = threadIdx.x >> 6;
  const int lane = threadIdx.x & 63;
  const int n = blockIdx.x * 4 + wave;
  if (n >= N_NODES) return;
  const int beg = rowptr[n];
  const int end = rowptr[n + 1];

  float ax = 0.f, ay = 0.f;
  int i = beg;
  for (; i + 3 < end; i += 4) {
    int s0 = col[i], s1 = col[i + 1], s2 = col[i + 2], s3 = col[i + 3];
    f16x2 v0 = *(const f16x2*)(M + (long)s0 * HIDDEN + lane * 2);
    f16x2 v1 = *(const f16x2*)(M + (long)s1 * HIDDEN + lane * 2);
    f16x2 v2 = *(const f16x2*)(M + (long)s2 * HIDDEN + lane * 2);
    f16x2 v3 = *(const f16x2*)(M + (long)s3 * HIDDEN + lane * 2);
    ax += (float)v0[0] + (float)v1[0] + (float)v2[0] + (float)v3[0];
    ay += (float)v0[1] + (float)v1[1] + (float)v2[1] + (float)v3[1];
  }
  for (; i < end; ++i) {
    f16x2 v = *(const f16x2*)(M + (long)col[i] * HIDDEN + lane * 2);
    ax += (float)v[0];
    ay += (float)v[1];
  }
  float s = nd[n];
  float sn = ns[n];
  float ox = fmaxf(ax * s + b[lane * 2], 0.f) * sn;
  float oy = fmaxf(ay * s + b[lane * 2 + 1], 0.f) * sn;
  f16x2 o;
  o[0] = (f16)ox;
  o[1] = (f16)oy;
  *(f16x2*)(out + (long)n * HIDDEN + lane * 2) = o;
}

__global__ __launch_bounds__(256) void gather2_kernel(
    const f16* __restrict__ M, const int* __restrict__ rowptr,
    const int* __restrict__ col, const float* __restrict__ nd,
    const float* __restrict__ b, float* __restrict__ out) {
  const int wave = threadIdx.x >> 6;
  const int lane = threadIdx.x & 63;
  const int n = blockIdx.x * 4 + wave;
  if (n >= N_NODES) return;
  const int beg = rowptr[n];
  const int end = rowptr[n + 1];

  float acc = 0.f;
  int i = beg;
  for (; i + 3 < end; i += 4) {
    int s0 = col[i], s1 = col[i + 1], s2 = col[i + 2], s3 = col[i + 3];
    acc += (float)M[(long)s0 * OUT_FEATS + lane] +
           (float)M[(long)s1 * OUT_FEATS + lane] +
           (float)M[(long)s2 * OUT_FEATS + lane] +
           (float)M[(long)s3 * OUT_FEATS + lane];
  }
  for (; i < end; ++i) acc += (float)M[(long)col[i] * OUT_FEATS + lane];
  out[(long)n * OUT_FEATS + lane] = acc * nd[n] + b[lane];
}

extern "C" void kernel_launch(void* const* d_in, const int* in_sizes, int n_in,
                              void* d_out, int out_size, void* d_ws,
                              size_t ws_size, hipStream_t stream) {
  const float* x = (const float*)d_in[0];
  const int* src = (const int*)d_in[1];
  const int* dst = (const int*)d_in[2];
  const float* W1 = (const float*)d_in[3];
  const float* b1 = (const float*)d_in[4];
  const float* W2 = (const float*)d_in[5];
  const float* b2 = (const float*)d_in[6];
  float* out = (float*)d_out;

  // ---- workspace layout
  int* wi = (int*)d_ws;
  int* partial = wi;            // [256]
  int* rowptr = wi + 256;       // [50001] (pad to 50004)
  int* deg_in = wi + 50260;     // [50000]
  int* col = wi + 100260;       // [800000] -> ends at int 900260
  float* wf = (float*)d_ws + 900260;
  float* norm_src = wf;         // [50000]
  float* norm_dst = wf + 50000; // [50000]
  f16* fh = (f16*)(wf + 100000);
  f16* W1T = fh;                // [128*256]
  f16* W2T = fh + 128 * 256;    // [64*128]
  f16* m1 = fh + 128 * 256 + 64 * 128;  // [50048*128]
  f16* h1p = m1 + (long)50048 * 128;    // [50048*128]
  f16* m2 = h1p + (long)50048 * 128;    // [50048*64]

  // hist/cursor overlay on m1's region (dead before gemm1 writes m1)
  int* hist_src = (int*)m1;                    // [NCOPY*N_NODES]
  int* hist_dst = hist_src + NCOPY * N_NODES;  // [NCOPY*N_NODES] -> pref
  int* cursor = hist_dst + NCOPY * N_NODES;    // [NCOPY*N_NODES]

  const int nb_nodes = (N_NODES + 255) / 256;  // 196
  const int nb_edges = (N_EDGES + 255) / 256;  // 3125

  // ---- degrees + norms + CSR (privatized atomics)
  hipMemsetAsync(hist_src, 0, 2L * NCOPY * N_NODES * sizeof(int), stream);
  hist_kernel<<<nb_edges, 256, 0, stream>>>(src, dst, hist_src, hist_dst);
  reduce_kernel<<<nb_nodes, 256, 0, stream>>>(hist_src, hist_dst, deg_in,
                                              norm_src, norm_dst);
  scan1<<<nb_nodes, 256, 0, stream>>>(deg_in, partial);
  scan2<<<1, 256, 0, stream>>>(partial, nb_nodes);
  scan3<<<nb_nodes, 256, 0, stream>>>(deg_in, partial, rowptr);
  cursor_init<<<(NCOPY * N_NODES + 255) / 256, 256, 0, stream>>>(
      rowptr, hist_dst, cursor);
  fill_csr<<<nb_edges, 256, 0, stream>>>(src, dst, cursor, col);
  wtrans<<<(128 * 256 + 64 * 128 + 255) / 256, 256, 0, stream>>>(W1, W2, W1T,
                                                                 W2T);

  // ---- layer 1
  gemm_mfma<IN_FEATS, HIDDEN, true>
      <<<(N_NODES + 127) / 128, 256, 0, stream>>>(x, W1T, norm_src, m1);
  gather1_kernel<<<(N_NODES + 3) / 4, 256, 0, stream>>>(m1, rowptr, col,
                                                        norm_dst, norm_src, b1,
                                                        h1p);

  // ---- layer 2
  gemm_mfma<HIDDEN, OUT_FEATS, false>
      <<<(N_NODES + 127) / 128, 256, 0, stream>>>(h1p, W2T, norm_src, m2);
  gather2_kernel<<<(N_NODES + 3) / 4, 256, 0, stream>>>(m2, rowptr, col,
                                                        norm_dst, b2, out);
}

// Round 5
// 265.148 us; speedup vs baseline: 4.1292x; 1.2456x over previous
//
#include <hip/hip_runtime.h>

#define N_NODES 50000
#define N_EDGES 800000
#define IN_FEATS 256
#define HIDDEN 128
#define OUT_FEATS 64

// ---- LDS-histogram decomposition ----
#define NB 8192              // bins per range (32 KB LDS per array)
#define NRANGE 7             // ceil(50000/8192)
#define NBT (NRANGE * NB)    // 57344 padded bins per copy
#define NCHUNK 64            // edge chunks (= privatized copies)
#define EPC 12500            // edges per chunk (64*12500 = 800000)

typedef _Float16 f16;
typedef _Float16 f16x2 __attribute__((ext_vector_type(2)));
typedef _Float16 f16x8 __attribute__((ext_vector_type(8)));
typedef float f32x4 __attribute__((ext_vector_type(4)));

// ---------------------------------------------------------- LDS histogram
// Block (r,c): scan chunk c, count nodes in range r into LDS, flush with
// PLAIN stores to hist[c][.]. Zero global atomics (they bypass L2 on gfx950:
// R3 showed 32 B HBM-side traffic per atomic regardless of locality).
__global__ __launch_bounds__(256) void hist_kernel(
    const int* __restrict__ src, const int* __restrict__ dst,
    int* __restrict__ hist_src, int* __restrict__ hist_dst) {
  __shared__ int ls[NB];
  __shared__ int ld2[NB];
  const int r = blockIdx.x % NRANGE;
  const int c = blockIdx.x / NRANGE;
  const int lo = r * NB;
  for (int i = threadIdx.x; i < NB; i += 256) {
    ls[i] = 0;
    ld2[i] = 0;
  }
  __syncthreads();
  const int4* s4 = (const int4*)(src + c * EPC);
  const int4* d4 = (const int4*)(dst + c * EPC);
  for (int i = threadIdx.x; i < EPC / 4; i += 256) {
    int4 s = s4[i];
    int4 d = d4[i];
    unsigned b;
    b = (unsigned)(s.x - lo); if (b < NB) atomicAdd(&ls[b], 1);
    b = (unsigned)(s.y - lo); if (b < NB) atomicAdd(&ls[b], 1);
    b = (unsigned)(s.z - lo); if (b < NB) atomicAdd(&ls[b], 1);
    b = (unsigned)(s.w - lo); if (b < NB) atomicAdd(&ls[b], 1);
    b = (unsigned)(d.x - lo); if (b < NB) atomicAdd(&ld2[b], 1);
    b = (unsigned)(d.y - lo); if (b < NB) atomicAdd(&ld2[b], 1);
    b = (unsigned)(d.z - lo); if (b < NB) atomicAdd(&ld2[b], 1);
    b = (unsigned)(d.w - lo); if (b < NB) atomicAdd(&ld2[b], 1);
  }
  __syncthreads();
  int* hs = hist_src + (long)c * NBT + lo;
  int* hd = hist_dst + (long)c * NBT + lo;
  for (int i = threadIdx.x; i < NB; i += 256) {
    hs[i] = ls[i];
    hd[i] = ld2[i];
  }
}

// sum copies -> norms; turn hist_dst into exclusive prefix over copies.
__global__ __launch_bounds__(256) void reduce_kernel(
    const int* __restrict__ hist_src, int* __restrict__ hist_dst,
    int* __restrict__ deg_in, float* __restrict__ norm_src,
    float* __restrict__ norm_dst) {
  int n = blockIdx.x * 256 + threadIdx.x;
  if (n >= N_NODES) return;
  int so = 0;
#pragma unroll 8
  for (int c = 0; c < NCHUNK; ++c) so += hist_src[(long)c * NBT + n];
  norm_src[n] = rsqrtf((float)max(so, 1));
  int run = 0;
#pragma unroll 8
  for (int c = 0; c < NCHUNK; ++c) {
    int t = hist_dst[(long)c * NBT + n];
    hist_dst[(long)c * NBT + n] = run;  // exclusive prefix (per-copy base)
    run += t;
  }
  deg_in[n] = run;
  norm_dst[n] = rsqrtf((float)max(run, 1));
}

// ------------------------------------------------------------- prefix scan
__global__ __launch_bounds__(256) void scan1(const int* __restrict__ deg,
                                             int* __restrict__ partial) {
  __shared__ int sd[256];
  int i = blockIdx.x * 256 + threadIdx.x;
  sd[threadIdx.x] = (i < N_NODES) ? deg[i] : 0;
  __syncthreads();
  for (int s = 128; s > 0; s >>= 1) {
    if (threadIdx.x < s) sd[threadIdx.x] += sd[threadIdx.x + s];
    __syncthreads();
  }
  if (threadIdx.x == 0) partial[blockIdx.x] = sd[0];
}

__global__ __launch_bounds__(256) void scan2(int* __restrict__ partial,
                                             int nb) {
  __shared__ int sd[256];
  int v = (threadIdx.x < nb) ? partial[threadIdx.x] : 0;
  sd[threadIdx.x] = v;
  __syncthreads();
  for (int off = 1; off < 256; off <<= 1) {
    int t = sd[threadIdx.x] +
            ((threadIdx.x >= off) ? sd[threadIdx.x - off] : 0);
    __syncthreads();
    sd[threadIdx.x] = t;
    __syncthreads();
  }
  if (threadIdx.x < nb) partial[threadIdx.x] = sd[threadIdx.x] - v;  // excl
}

__global__ __launch_bounds__(256) void scan3(const int* __restrict__ deg,
                                             const int* __restrict__ partial,
                                             int* __restrict__ rowptr) {
  __shared__ int sd[256];
  int i = blockIdx.x * 256 + threadIdx.x;
  int v = (i < N_NODES) ? deg[i] : 0;
  sd[threadIdx.x] = v;
  __syncthreads();
  for (int off = 1; off < 256; off <<= 1) {
    int t = sd[threadIdx.x] +
            ((threadIdx.x >= off) ? sd[threadIdx.x - off] : 0);
    __syncthreads();
    sd[threadIdx.x] = t;
    __syncthreads();
  }
  if (i < N_NODES) rowptr[i] = partial[blockIdx.x] + sd[threadIdx.x] - v;
  if (blockIdx.x == 0 && threadIdx.x == 0) rowptr[N_NODES] = N_EDGES;
}

// ------------------------------------------------------------- CSR fill
// Same (r,c) grid and chunk mapping as hist_kernel; cursors live in LDS,
// positions via LDS atomics, one plain scattered store per edge.
__global__ __launch_bounds__(256) void fill_csr(
    const int* __restrict__ src, const int* __restrict__ dst,
    const int* __restrict__ rowptr, const int* __restrict__ pref,
    int* __restrict__ col) {
  __shared__ int cur[NB];
  const int r = blockIdx.x % NRANGE;
  const int c = blockIdx.x / NRANGE;
  const int lo = r * NB;
  for (int i = threadIdx.x; i < NB; i += 256) {
    int n = lo + i;
    cur[i] = (n < N_NODES) ? rowptr[n] + pref[(long)c * NBT + n] : 0;
  }
  __syncthreads();
  const int4* s4 = (const int4*)(src + c * EPC);
  const int4* d4 = (const int4*)(dst + c * EPC);
  for (int i = threadIdx.x; i < EPC / 4; i += 256) {
    int4 s = s4[i];
    int4 d = d4[i];
    unsigned b;
    b = (unsigned)(d.x - lo);
    if (b < NB) col[atomicAdd(&cur[b], 1)] = s.x;
    b = (unsigned)(d.y - lo);
    if (b < NB) col[atomicAdd(&cur[b], 1)] = s.y;
    b = (unsigned)(d.z - lo);
    if (b < NB) col[atomicAdd(&cur[b], 1)] = s.z;
    b = (unsigned)(d.w - lo);
    if (b < NB) col[atomicAdd(&cur[b], 1)] = s.w;
  }
}

// ------------------------------------------------------------- W transpose
__global__ __launch_bounds__(256) void wtrans(const float* __restrict__ W1,
                                              const float* __restrict__ W2,
                                              f16* __restrict__ W1T,
                                              f16* __restrict__ W2T) {
  int i = blockIdx.x * 256 + threadIdx.x;
  if (i < 128 * 256) {
    int n = i >> 8, k = i & 255;
    W1T[i] = (f16)W1[k * 128 + n];
  } else if (i < 128 * 256 + 64 * 128) {
    int j = i - 128 * 256;
    int n = j >> 7, k = j & 127;
    W2T[j] = (f16)W2[k * 64 + n];
  }
}

// ------------------------------------------------------------- MFMA GEMM
template <int K, int NC, bool FP32IN>
__global__ __launch_bounds__(256) void gemm_mfma(
    const void* __restrict__ Xv, const f16* __restrict__ WT,
    const float* __restrict__ ns, f16* __restrict__ Mout) {
  constexpr int KI = K / 32;
  constexpr int NT = NC / 16;
  const int wave = threadIdx.x >> 6;
  const int lane = threadIdx.x & 63;
  const int m = lane & 15;
  const int q = lane >> 4;
  const int wrow0 = blockIdx.x * 128 + wave * 32;

  const int ra0 = min(wrow0 + m, N_NODES - 1);
  const int ra1 = min(wrow0 + 16 + m, N_NODES - 1);
  const float s0 = FP32IN ? ns[ra0] : 0.f;
  const float s1 = FP32IN ? ns[ra1] : 0.f;

  f32x4 acc[2][NT];
#pragma unroll
  for (int ab = 0; ab < 2; ++ab)
#pragma unroll
    for (int t = 0; t < NT; ++t) acc[ab][t] = (f32x4){0.f, 0.f, 0.f, 0.f};

#pragma unroll
  for (int ki = 0; ki < KI; ++ki) {
    const int kbase = ki * 32 + q * 8;
    f16x8 a0, a1;
    if (FP32IN) {
      const float* X = (const float*)Xv;
      const float* p0 = X + (long)ra0 * K + kbase;
      const float* p1 = X + (long)ra1 * K + kbase;
      float4 u0 = *(const float4*)p0;
      float4 u1 = *(const float4*)(p0 + 4);
      float4 w0 = *(const float4*)p1;
      float4 w1 = *(const float4*)(p1 + 4);
      a0[0] = (f16)(u0.x * s0); a0[1] = (f16)(u0.y * s0);
      a0[2] = (f16)(u0.z * s0); a0[3] = (f16)(u0.w * s0);
      a0[4] = (f16)(u1.x * s0); a0[5] = (f16)(u1.y * s0);
      a0[6] = (f16)(u1.z * s0); a0[7] = (f16)(u1.w * s0);
      a1[0] = (f16)(w0.x * s1); a1[1] = (f16)(w0.y * s1);
      a1[2] = (f16)(w0.z * s1); a1[3] = (f16)(w0.w * s1);
      a1[4] = (f16)(w1.x * s1); a1[5] = (f16)(w1.y * s1);
      a1[6] = (f16)(w1.z * s1); a1[7] = (f16)(w1.w * s1);
    } else {
      const f16* X = (const f16*)Xv;
      a0 = *(const f16x8*)(X + (long)ra0 * K + kbase);
      a1 = *(const f16x8*)(X + (long)ra1 * K + kbase);
    }
#pragma unroll
    for (int t = 0; t < NT; ++t) {
      f16x8 b = *(const f16x8*)(WT + (long)(t * 16 + m) * K + kbase);
      acc[0][t] =
          __builtin_amdgcn_mfma_f32_16x16x32_f16(a0, b, acc[0][t], 0, 0, 0);
      acc[1][t] =
          __builtin_amdgcn_mfma_f32_16x16x32_f16(a1, b, acc[1][t], 0, 0, 0);
    }
  }

#pragma unroll
  for (int ab = 0; ab < 2; ++ab)
#pragma unroll
    for (int r = 0; r < 4; ++r) {
      int row = wrow0 + ab * 16 + q * 4 + r;
      if (row < N_NODES) {
#pragma unroll
        for (int t = 0; t < NT; ++t)
          Mout[(long)row * NC + t * 16 + m] = (f16)acc[ab][t][r];
      }
    }
}

// ------------------------------------------------------------- gather-agg
__global__ __launch_bounds__(256) void gather1_kernel(
    const f16* __restrict__ M, const int* __restrict__ rowptr,
    const int* __restrict__ col, const float* __restrict__ nd,
    const float* __restrict__ ns, const float* __restrict__ b,
    f16* __restrict__ out) {
  const int wave = threadIdx.x >> 6;
  const int lane = threadIdx.x & 63;
  const int n = blockIdx.x * 4 + wave;
  if (n >= N_NODES) return;
  const int beg = rowptr[n];
  const int end = rowptr[n + 1];

  float ax = 0.f, ay = 0.f;
  int i = beg;
  for (; i + 3 < end; i += 4) {
    int s0 = col[i], s1 = col[i + 1], s2 = col[i + 2], s3 = col[i + 3];
    f16x2 v0 = *(const f16x2*)(M + (long)s0 * HIDDEN + lane * 2);
    f16x2 v1 = *(const f16x2*)(M + (long)s1 * HIDDEN + lane * 2);
    f16x2 v2 = *(const f16x2*)(M + (long)s2 * HIDDEN + lane * 2);
    f16x2 v3 = *(const f16x2*)(M + (long)s3 * HIDDEN + lane * 2);
    ax += (float)v0[0] + (float)v1[0] + (float)v2[0] + (float)v3[0];
    ay += (float)v0[1] + (float)v1[1] + (float)v2[1] + (float)v3[1];
  }
  for (; i < end; ++i) {
    f16x2 v = *(const f16x2*)(M + (long)col[i] * HIDDEN + lane * 2);
    ax += (float)v[0];
    ay += (float)v[1];
  }
  float s = nd[n];
  float sn = ns[n];
  float ox = fmaxf(ax * s + b[lane * 2], 0.f) * sn;
  float oy = fmaxf(ay * s + b[lane * 2 + 1], 0.f) * sn;
  f16x2 o;
  o[0] = (f16)ox;
  o[1] = (f16)oy;
  *(f16x2*)(out + (long)n * HIDDEN + lane * 2) = o;
}

__global__ __launch_bounds__(256) void gather2_kernel(
    const f16* __restrict__ M, const int* __restrict__ rowptr,
    const int* __restrict__ col, const float* __restrict__ nd,
    const float* __restrict__ b, float* __restrict__ out) {
  const int wave = threadIdx.x >> 6;
  const int lane = threadIdx.x & 63;
  const int n = blockIdx.x * 4 + wave;
  if (n >= N_NODES) return;
  const int beg = rowptr[n];
  const int end = rowptr[n + 1];

  float acc = 0.f;
  int i = beg;
  for (; i + 3 < end; i += 4) {
    int s0 = col[i], s1 = col[i + 1], s2 = col[i + 2], s3 = col[i + 3];
    acc += (float)M[(long)s0 * OUT_FEATS + lane] +
           (float)M[(long)s1 * OUT_FEATS + lane] +
           (float)M[(long)s2 * OUT_FEATS + lane] +
           (float)M[(long)s3 * OUT_FEATS + lane];
  }
  for (; i < end; ++i) acc += (float)M[(long)col[i] * OUT_FEATS + lane];
  out[(long)n * OUT_FEATS + lane] = acc * nd[n] + b[lane];
}

extern "C" void kernel_launch(void* const* d_in, const int* in_sizes, int n_in,
                              void* d_out, int out_size, void* d_ws,
                              size_t ws_size, hipStream_t stream) {
  const float* x = (const float*)d_in[0];
  const int* src = (const int*)d_in[1];
  const int* dst = (const int*)d_in[2];
  const float* W1 = (const float*)d_in[3];
  const float* b1 = (const float*)d_in[4];
  const float* W2 = (const float*)d_in[5];
  const float* b2 = (const float*)d_in[6];
  float* out = (float*)d_out;

  // ---- workspace layout
  int* wi = (int*)d_ws;
  int* partial = wi;            // [256]
  int* rowptr = wi + 256;       // [50001] (pad to 50004)
  int* deg_in = wi + 50260;     // [50000]
  int* col = wi + 100260;       // [800000] -> ends at int 900260
  float* wf = (float*)d_ws + 900260;
  float* norm_src = wf;         // [50000]
  float* norm_dst = wf + 50000; // [50000]
  f16* fh = (f16*)(wf + 100000);
  f16* W1T = fh;                // [128*256]
  f16* W2T = fh + 128 * 256;    // [64*128]
  f16* m1 = fh + 128 * 256 + 64 * 128;  // [50048*128]
  f16* h1p = m1 + (long)50048 * 128;    // [50048*128]
  f16* m2 = h1p + (long)50048 * 128;    // [50048*64]

  // hist overlay on m1/h1p/m2 region: 2 * 64 * 57344 * 4 B = 29.4 MB,
  // region = 32 MB; dead before gemm1 writes m1 (stream-ordered).
  int* hist_src = (int*)m1;                       // [NCHUNK*NBT]
  int* hist_dst = hist_src + (long)NCHUNK * NBT;  // [NCHUNK*NBT] -> pref

  const int nb_nodes = (N_NODES + 255) / 256;  // 196

  // ---- degrees + norms + CSR (no global atomics)
  hist_kernel<<<NRANGE * NCHUNK, 256, 0, stream>>>(src, dst, hist_src,
                                                   hist_dst);
  reduce_kernel<<<nb_nodes, 256, 0, stream>>>(hist_src, hist_dst, deg_in,
                                              norm_src, norm_dst);
  scan1<<<nb_nodes, 256, 0, stream>>>(deg_in, partial);
  scan2<<<1, 256, 0, stream>>>(partial, nb_nodes);
  scan3<<<nb_nodes, 256, 0, stream>>>(deg_in, partial, rowptr);
  fill_csr<<<NRANGE * NCHUNK, 256, 0, stream>>>(src, dst, rowptr, hist_dst,
                                                col);
  wtrans<<<(128 * 256 + 64 * 128 + 255) / 256, 256, 0, stream>>>(W1, W2, W1T,
                                                                 W2T);

  // ---- layer 1
  gemm_mfma<IN_FEATS, HIDDEN, true>
      <<<(N_NODES + 127) / 128, 256, 0, stream>>>(x, W1T, norm_src, m1);
  gather1_kernel<<<(N_NODES + 3) / 4, 256, 0, stream>>>(m1, rowptr, col,
                                                        norm_dst, norm_src, b1,
                                                        h1p);

  // ---- layer 2
  gemm_mfma<HIDDEN, OUT_FEATS, false>
      <<<(N_NODES + 127) / 128, 256, 0, stream>>>(h1p, W2T, norm_src, m2);
  gather2_kernel<<<(N_NODES + 3) / 4, 256, 0, stream>>>(m2, rowptr, col,
                                                        norm_dst, b2, out);
}

// Round 6
// 249.640 us; speedup vs baseline: 4.3858x; 1.0621x over previous
//
#include <hip/hip_runtime.h>

#define N_NODES 50000
#define N_EDGES 800000
#define IN_FEATS 256
#define HIDDEN 128
#define OUT_FEATS 64

// ---- LDS-histogram decomposition ----
#define NB 8192              // bins per range (32 KB LDS per array)
#define NRANGE 7             // ceil(50000/8192)
#define NBT (NRANGE * NB)    // 57344 padded bins per copy
#define NCHUNK 64            // edge chunks (= privatized copies)
#define EPC 12500            // edges per chunk (64*12500 = 800000)

typedef _Float16 f16;
typedef _Float16 f16x2 __attribute__((ext_vector_type(2)));
typedef _Float16 f16x8 __attribute__((ext_vector_type(8)));
typedef float f32x4 __attribute__((ext_vector_type(4)));

// ---------------------------------------------------------- LDS histogram
// Zero global atomics (gfx950 global atomics cost ~32B beyond-L2 traffic
// each, regardless of locality — measured R3/R4).
__global__ __launch_bounds__(256) void hist_kernel(
    const int* __restrict__ src, const int* __restrict__ dst,
    int* __restrict__ hist_src, int* __restrict__ hist_dst) {
  __shared__ int ls[NB];
  __shared__ int ld2[NB];
  const int r = blockIdx.x % NRANGE;
  const int c = blockIdx.x / NRANGE;
  const int lo = r * NB;
  for (int i = threadIdx.x; i < NB; i += 256) {
    ls[i] = 0;
    ld2[i] = 0;
  }
  __syncthreads();
  const int4* s4 = (const int4*)(src + c * EPC);
  const int4* d4 = (const int4*)(dst + c * EPC);
  for (int i = threadIdx.x; i < EPC / 4; i += 256) {
    int4 s = s4[i];
    int4 d = d4[i];
    unsigned b;
    b = (unsigned)(s.x - lo); if (b < NB) atomicAdd(&ls[b], 1);
    b = (unsigned)(s.y - lo); if (b < NB) atomicAdd(&ls[b], 1);
    b = (unsigned)(s.z - lo); if (b < NB) atomicAdd(&ls[b], 1);
    b = (unsigned)(s.w - lo); if (b < NB) atomicAdd(&ls[b], 1);
    b = (unsigned)(d.x - lo); if (b < NB) atomicAdd(&ld2[b], 1);
    b = (unsigned)(d.y - lo); if (b < NB) atomicAdd(&ld2[b], 1);
    b = (unsigned)(d.z - lo); if (b < NB) atomicAdd(&ld2[b], 1);
    b = (unsigned)(d.w - lo); if (b < NB) atomicAdd(&ld2[b], 1);
  }
  __syncthreads();
  int* hs = hist_src + (long)c * NBT + lo;
  int* hd = hist_dst + (long)c * NBT + lo;
  for (int i = threadIdx.x; i < NB; i += 256) {
    hs[i] = ls[i];
    hd[i] = ld2[i];
  }
}

// sum copies -> norms; hist_dst -> exclusive prefix over copies; also emits
// per-256-node-block degree sums (replaces scan1 — same blocking).
__global__ __launch_bounds__(256) void reduce_kernel(
    const int* __restrict__ hist_src, int* __restrict__ hist_dst,
    int* __restrict__ deg_in, float* __restrict__ norm_src,
    float* __restrict__ norm_dst, int* __restrict__ partial) {
  int n = blockIdx.x * 256 + threadIdx.x;
  int run = 0;
  if (n < N_NODES) {
    int so = 0;
#pragma unroll 8
    for (int c = 0; c < NCHUNK; ++c) so += hist_src[(long)c * NBT + n];
    norm_src[n] = rsqrtf((float)max(so, 1));
#pragma unroll 8
    for (int c = 0; c < NCHUNK; ++c) {
      int t = hist_dst[(long)c * NBT + n];
      hist_dst[(long)c * NBT + n] = run;  // exclusive prefix (per-copy base)
      run += t;
    }
    deg_in[n] = run;
    norm_dst[n] = rsqrtf((float)max(run, 1));
  }
  __shared__ int sd[256];
  sd[threadIdx.x] = run;
  __syncthreads();
  for (int s = 128; s > 0; s >>= 1) {
    if (threadIdx.x < s) sd[threadIdx.x] += sd[threadIdx.x + s];
    __syncthreads();
  }
  if (threadIdx.x == 0) partial[blockIdx.x] = sd[0];
}

// ------------------------------------------------------------- prefix scan
__global__ __launch_bounds__(256) void scan2(int* __restrict__ partial,
                                             int nb) {
  __shared__ int sd[256];
  int v = (threadIdx.x < nb) ? partial[threadIdx.x] : 0;
  sd[threadIdx.x] = v;
  __syncthreads();
  for (int off = 1; off < 256; off <<= 1) {
    int t = sd[threadIdx.x] +
            ((threadIdx.x >= off) ? sd[threadIdx.x - off] : 0);
    __syncthreads();
    sd[threadIdx.x] = t;
    __syncthreads();
  }
  if (threadIdx.x < nb) partial[threadIdx.x] = sd[threadIdx.x] - v;  // excl
}

__global__ __launch_bounds__(256) void scan3(const int* __restrict__ deg,
                                             const int* __restrict__ partial,
                                             int* __restrict__ rowptr) {
  __shared__ int sd[256];
  int i = blockIdx.x * 256 + threadIdx.x;
  int v = (i < N_NODES) ? deg[i] : 0;
  sd[threadIdx.x] = v;
  __syncthreads();
  for (int off = 1; off < 256; off <<= 1) {
    int t = sd[threadIdx.x] +
            ((threadIdx.x >= off) ? sd[threadIdx.x - off] : 0);
    __syncthreads();
    sd[threadIdx.x] = t;
    __syncthreads();
  }
  if (i < N_NODES) rowptr[i] = partial[blockIdx.x] + sd[threadIdx.x] - v;
  if (blockIdx.x == 0 && threadIdx.x == 0) rowptr[N_NODES] = N_EDGES;
}

// ------------------------------------------------------------- CSR fill
__global__ __launch_bounds__(256) void fill_csr(
    const int* __restrict__ src, const int* __restrict__ dst,
    const int* __restrict__ rowptr, const int* __restrict__ pref,
    int* __restrict__ col) {
  __shared__ int cur[NB];
  const int r = blockIdx.x % NRANGE;
  const int c = blockIdx.x / NRANGE;
  const int lo = r * NB;
  for (int i = threadIdx.x; i < NB; i += 256) {
    int n = lo + i;
    cur[i] = (n < N_NODES) ? rowptr[n] + pref[(long)c * NBT + n] : 0;
  }
  __syncthreads();
  const int4* s4 = (const int4*)(src + c * EPC);
  const int4* d4 = (const int4*)(dst + c * EPC);
  for (int i = threadIdx.x; i < EPC / 4; i += 256) {
    int4 s = s4[i];
    int4 d = d4[i];
    unsigned b;
    b = (unsigned)(d.x - lo);
    if (b < NB) col[atomicAdd(&cur[b], 1)] = s.x;
    b = (unsigned)(d.y - lo);
    if (b < NB) col[atomicAdd(&cur[b], 1)] = s.y;
    b = (unsigned)(d.z - lo);
    if (b < NB) col[atomicAdd(&cur[b], 1)] = s.z;
    b = (unsigned)(d.w - lo);
    if (b < NB) col[atomicAdd(&cur[b], 1)] = s.w;
  }
}

// ------------------------------------------------------------- W transpose
__global__ __launch_bounds__(256) void wtrans(const float* __restrict__ W1,
                                              const float* __restrict__ W2,
                                              f16* __restrict__ W1T,
                                              f16* __restrict__ W2T) {
  int i = blockIdx.x * 256 + threadIdx.x;
  if (i < 128 * 256) {
    int n = i >> 8, k = i & 255;
    W1T[i] = (f16)W1[k * 128 + n];
  } else if (i < 128 * 256 + 64 * 128) {
    int j = i - 128 * 256;
    int n = j >> 7, k = j & 127;
    W2T[j] = (f16)W2[k * 64 + n];
  }
}

// ------------------------------------------------------------- MFMA GEMM
template <int K, int NC, bool FP32IN>
__global__ __launch_bounds__(256) void gemm_mfma(
    const void* __restrict__ Xv, const f16* __restrict__ WT,
    const float* __restrict__ ns, f16* __restrict__ Mout) {
  constexpr int KI = K / 32;
  constexpr int NT = NC / 16;
  const int wave = threadIdx.x >> 6;
  const int lane = threadIdx.x & 63;
  const int m = lane & 15;
  const int q = lane >> 4;
  const int wrow0 = blockIdx.x * 128 + wave * 32;

  const int ra0 = min(wrow0 + m, N_NODES - 1);
  const int ra1 = min(wrow0 + 16 + m, N_NODES - 1);
  const float s0 = FP32IN ? ns[ra0] : 0.f;
  const float s1 = FP32IN ? ns[ra1] : 0.f;

  f32x4 acc[2][NT];
#pragma unroll
  for (int ab = 0; ab < 2; ++ab)
#pragma unroll
    for (int t = 0; t < NT; ++t) acc[ab][t] = (f32x4){0.f, 0.f, 0.f, 0.f};

#pragma unroll
  for (int ki = 0; ki < KI; ++ki) {
    const int kbase = ki * 32 + q * 8;
    f16x8 a0, a1;
    if (FP32IN) {
      const float* X = (const float*)Xv;
      const float* p0 = X + (long)ra0 * K + kbase;
      const float* p1 = X + (long)ra1 * K + kbase;
      float4 u0 = *(const float4*)p0;
      float4 u1 = *(const float4*)(p0 + 4);
      float4 w0 = *(const float4*)p1;
      float4 w1 = *(const float4*)(p1 + 4);
      a0[0] = (f16)(u0.x * s0); a0[1] = (f16)(u0.y * s0);
      a0[2] = (f16)(u0.z * s0); a0[3] = (f16)(u0.w * s0);
      a0[4] = (f16)(u1.x * s0); a0[5] = (f16)(u1.y * s0);
      a0[6] = (f16)(u1.z * s0); a0[7] = (f16)(u1.w * s0);
      a1[0] = (f16)(w0.x * s1); a1[1] = (f16)(w0.y * s1);
      a1[2] = (f16)(w0.z * s1); a1[3] = (f16)(w0.w * s1);
      a1[4] = (f16)(w1.x * s1); a1[5] = (f16)(w1.y * s1);
      a1[6] = (f16)(w1.z * s1); a1[7] = (f16)(w1.w * s1);
    } else {
      const f16* X = (const f16*)Xv;
      a0 = *(const f16x8*)(X + (long)ra0 * K + kbase);
      a1 = *(const f16x8*)(X + (long)ra1 * K + kbase);
    }
#pragma unroll
    for (int t = 0; t < NT; ++t) {
      f16x8 b = *(const f16x8*)(WT + (long)(t * 16 + m) * K + kbase);
      acc[0][t] =
          __builtin_amdgcn_mfma_f32_16x16x32_f16(a0, b, acc[0][t], 0, 0, 0);
      acc[1][t] =
          __builtin_amdgcn_mfma_f32_16x16x32_f16(a1, b, acc[1][t], 0, 0, 0);
    }
  }

#pragma unroll
  for (int ab = 0; ab < 2; ++ab)
#pragma unroll
    for (int r = 0; r < 4; ++r) {
      int row = wrow0 + ab * 16 + q * 4 + r;
      if (row < N_NODES) {
#pragma unroll
        for (int t = 0; t < NT; ++t)
          Mout[(long)row * NC + t * 16 + m] = (f16)acc[ab][t][r];
      }
    }
}

// ------------------------------------------------------------- gather-agg
// Wave = 1 dst node. Wave split into EPW groups of LPR lanes; each group
// owns one edge's row, reading f16x8 (16 B/lane, 1 KB/instr). Groups stride
// the CSR segment independently (no remainder logic); cross-group combine
// via __shfl_xor butterfly; group 0 does fused epilogue + 16 B stores.
__global__ __launch_bounds__(256) void gather1_kernel(
    const f16* __restrict__ M, const int* __restrict__ rowptr,
    const int* __restrict__ col, const float* __restrict__ nd,
    const float* __restrict__ ns, const float* __restrict__ b,
    f16* __restrict__ out) {
  constexpr int LPR = 16;       // 128 f16 = 256 B row / 16 B per lane
  constexpr int EPW = 64 / LPR; // 4 edges in parallel
  const int wave = threadIdx.x >> 6;
  const int lane = threadIdx.x & 63;
  const int g = lane / LPR;
  const int t = lane % LPR;
  const int n = blockIdx.x * 4 + wave;
  if (n >= N_NODES) return;
  const int beg = rowptr[n];
  const int end = rowptr[n + 1];

  float acc[8];
#pragma unroll
  for (int j = 0; j < 8; ++j) acc[j] = 0.f;

  int i = beg + g;
  for (; i + EPW < end; i += 2 * EPW) {
    int s0 = col[i];
    int s1 = col[i + EPW];
    f16x8 v0 = *(const f16x8*)(M + (long)s0 * HIDDEN + t * 8);
    f16x8 v1 = *(const f16x8*)(M + (long)s1 * HIDDEN + t * 8);
#pragma unroll
    for (int j = 0; j < 8; ++j) acc[j] += (float)v0[j] + (float)v1[j];
  }
  if (i < end) {
    int s0 = col[i];
    f16x8 v0 = *(const f16x8*)(M + (long)s0 * HIDDEN + t * 8);
#pragma unroll
    for (int j = 0; j < 8; ++j) acc[j] += (float)v0[j];
  }

#pragma unroll
  for (int m2 = LPR; m2 < 64; m2 <<= 1)
#pragma unroll
    for (int j = 0; j < 8; ++j) acc[j] += __shfl_xor(acc[j], m2, 64);

  if (g == 0) {
    float s = nd[n];
    float sn = ns[n];
    float4 bb0 = *(const float4*)(b + t * 8);
    float4 bb1 = *(const float4*)(b + t * 8 + 4);
    f16x8 o;
    o[0] = (f16)(fmaxf(acc[0] * s + bb0.x, 0.f) * sn);
    o[1] = (f16)(fmaxf(acc[1] * s + bb0.y, 0.f) * sn);
    o[2] = (f16)(fmaxf(acc[2] * s + bb0.z, 0.f) * sn);
    o[3] = (f16)(fmaxf(acc[3] * s + bb0.w, 0.f) * sn);
    o[4] = (f16)(fmaxf(acc[4] * s + bb1.x, 0.f) * sn);
    o[5] = (f16)(fmaxf(acc[5] * s + bb1.y, 0.f) * sn);
    o[6] = (f16)(fmaxf(acc[6] * s + bb1.z, 0.f) * sn);
    o[7] = (f16)(fmaxf(acc[7] * s + bb1.w, 0.f) * sn);
    *(f16x8*)(out + (long)n * HIDDEN + t * 8) = o;
  }
}

__global__ __launch_bounds__(256) void gather2_kernel(
    const f16* __restrict__ M, const int* __restrict__ rowptr,
    const int* __restrict__ col, const float* __restrict__ nd,
    const float* __restrict__ b, float* __restrict__ out) {
  constexpr int LPR = 8;        // 64 f16 = 128 B row / 16 B per lane
  constexpr int EPW = 64 / LPR; // 8 edges in parallel
  const int wave = threadIdx.x >> 6;
  const int lane = threadIdx.x & 63;
  const int g = lane / LPR;
  const int t = lane % LPR;
  const int n = blockIdx.x * 4 + wave;
  if (n >= N_NODES) return;
  const int beg = rowptr[n];
  const int end = rowptr[n + 1];

  float acc[8];
#pragma unroll
  for (int j = 0; j < 8; ++j) acc[j] = 0.f;

  int i = beg + g;
  for (; i + EPW < end; i += 2 * EPW) {
    int s0 = col[i];
    int s1 = col[i + EPW];
    f16x8 v0 = *(const f16x8*)(M + (long)s0 * OUT_FEATS + t * 8);
    f16x8 v1 = *(const f16x8*)(M + (long)s1 * OUT_FEATS + t * 8);
#pragma unroll
    for (int j = 0; j < 8; ++j) acc[j] += (float)v0[j] + (float)v1[j];
  }
  if (i < end) {
    int s0 = col[i];
    f16x8 v0 = *(const f16x8*)(M + (long)s0 * OUT_FEATS + t * 8);
#pragma unroll
    for (int j = 0; j < 8; ++j) acc[j] += (float)v0[j];
  }

#pragma unroll
  for (int m2 = LPR; m2 < 64; m2 <<= 1)
#pragma unroll
    for (int j = 0; j < 8; ++j) acc[j] += __shfl_xor(acc[j], m2, 64);

  if (g == 0) {
    float s = nd[n];
    float4 bb0 = *(const float4*)(b + t * 8);
    float4 bb1 = *(const float4*)(b + t * 8 + 4);
    float4 o0, o1;
    o0.x = acc[0] * s + bb0.x;
    o0.y = acc[1] * s + bb0.y;
    o0.z = acc[2] * s + bb0.z;
    o0.w = acc[3] * s + bb0.w;
    o1.x = acc[4] * s + bb1.x;
    o1.y = acc[5] * s + bb1.y;
    o1.z = acc[6] * s + bb1.z;
    o1.w = acc[7] * s + bb1.w;
    *(float4*)(out + (long)n * OUT_FEATS + t * 8) = o0;
    *(float4*)(out + (long)n * OUT_FEATS + t * 8 + 4) = o1;
  }
}

extern "C" void kernel_launch(void* const* d_in, const int* in_sizes, int n_in,
                              void* d_out, int out_size, void* d_ws,
                              size_t ws_size, hipStream_t stream) {
  const float* x = (const float*)d_in[0];
  const int* src = (const int*)d_in[1];
  const int* dst = (const int*)d_in[2];
  const float* W1 = (const float*)d_in[3];
  const float* b1 = (const float*)d_in[4];
  const float* W2 = (const float*)d_in[5];
  const float* b2 = (const float*)d_in[6];
  float* out = (float*)d_out;

  // ---- workspace layout
  int* wi = (int*)d_ws;
  int* partial = wi;            // [256]
  int* rowptr = wi + 256;       // [50001] (pad to 50004)
  int* deg_in = wi + 50260;     // [50000]
  int* col = wi + 100260;       // [800000] -> ends at int 900260
  float* wf = (float*)d_ws + 900260;
  float* norm_src = wf;         // [50000]
  float* norm_dst = wf + 50000; // [50000]
  f16* fh = (f16*)(wf + 100000);
  f16* W1T = fh;                // [128*256]
  f16* W2T = fh + 128 * 256;    // [64*128]
  f16* m1 = fh + 128 * 256 + 64 * 128;  // [50048*128]
  f16* h1p = m1 + (long)50048 * 128;    // [50048*128]
  f16* m2 = h1p + (long)50048 * 128;    // [50048*64]

  // hist overlay on m1/h1p/m2 region: 29.4 MB < 32 MB region; dead before
  // gemm1 writes m1 (stream-ordered).
  int* hist_src = (int*)m1;                       // [NCHUNK*NBT]
  int* hist_dst = hist_src + (long)NCHUNK * NBT;  // [NCHUNK*NBT] -> pref

  const int nb_nodes = (N_NODES + 255) / 256;  // 196

  // ---- degrees + norms + CSR (no global atomics)
  hist_kernel<<<NRANGE * NCHUNK, 256, 0, stream>>>(src, dst, hist_src,
                                                   hist_dst);
  reduce_kernel<<<nb_nodes, 256, 0, stream>>>(hist_src, hist_dst, deg_in,
                                              norm_src, norm_dst, partial);
  scan2<<<1, 256, 0, stream>>>(partial, nb_nodes);
  scan3<<<nb_nodes, 256, 0, stream>>>(deg_in, partial, rowptr);
  fill_csr<<<NRANGE * NCHUNK, 256, 0, stream>>>(src, dst, rowptr, hist_dst,
                                                col);
  wtrans<<<(128 * 256 + 64 * 128 + 255) / 256, 256, 0, stream>>>(W1, W2, W1T,
                                                                 W2T);

  // ---- layer 1
  gemm_mfma<IN_FEATS, HIDDEN, true>
      <<<(N_NODES + 127) / 128, 256, 0, stream>>>(x, W1T, norm_src, m1);
  gather1_kernel<<<(N_NODES + 3) / 4, 256, 0, stream>>>(m1, rowptr, col,
                                                        norm_dst, norm_src, b1,
                                                        h1p);

  // ---- layer 2
  gemm_mfma<HIDDEN, OUT_FEATS, false>
      <<<(N_NODES + 127) / 128, 256, 0, stream>>>(h1p, W2T, norm_src, m2);
  gather2_kernel<<<(N_NODES + 3) / 4, 256, 0, stream>>>(m2, rowptr, col,
                                                        norm_dst, b2, out);
}